// Round 14
// baseline (346.026 us; speedup 1.0000x reference)
//
#include <hip/hip_runtime.h>

// ---------------------------------------------------------------------------
// MHSelfAttention (Transformer-XL relative shift), MI355X gfx950
// B=4 L=1536 D=768 H=8 DQK=64 DV=96 NPF=96
// logits[b,h,i,j] = (Q*s+rwb)[i].K[j] + (Q*s+rrb)[i].rK[j-i+L-1]
// R24: staging-ablation hybrid — stage K+V (8x intra-block reuse), DIRECT
// rK loads (only 1-5 waves/subtile, avg 3.3x reuse; 3MB b-independent ->
// hottest L2 data). Completes R21(all-staged,147us)/R22(none,285us) matrix.
// Ring removed: LDS 70->38KB (Kt 8 + Vs 12 + Ps 18) -> 4 blocks/CU,
// 8 waves/SIMD = 2x TLP to heal barrier lockstep (R12 lesson). rK load
// addresses independent of content phase -> hoistable above [A] MFMAs.
// All else = R23: pre_k (vectorized cvt), qkv 128x128, out 64x64, combine.
// ---------------------------------------------------------------------------

typedef unsigned short u16;
typedef unsigned int   u32;

typedef __bf16 bf16x8_t __attribute__((ext_vector_type(8)));
typedef unsigned short u16x8_t __attribute__((ext_vector_type(8)));
typedef float f32x4_t __attribute__((ext_vector_type(4)));

union Frag { u16x8_t u; bf16x8_t b; };

__device__ __forceinline__ float bf2f(u16 v){
  union { u32 i; float f; } c; c.i = ((u32)v) << 16; return c.f;
}
__device__ __forceinline__ u16 f2bf(float f){
  union { float f; u32 i; } c; c.f = f;
  u32 r = c.i + 0x7FFFu + ((c.i >> 16) & 1u);
  return (u16)(r >> 16);
}
// HW RNE cast — 1 op vs 4-op manual f2bf
__device__ __forceinline__ u16 f2bf_hw(float f){
  __bf16 h = (__bf16)f;
  union { __bf16 h; u16 u; } c; c.h = h; return c.u;
}
__device__ __forceinline__ float frcp(float x){
#if __has_builtin(__builtin_amdgcn_rcpf)
  return __builtin_amdgcn_rcpf(x);
#else
  return 1.0f / x;
#endif
}

// DPP row_ror:N within 16-lane rows (VALU, no DS pipe).
template<int N>
__device__ __forceinline__ float ror16(float x){
  union { float f; int i; } c; c.f = x;
  int y = __builtin_amdgcn_update_dpp(0, c.i, 0x120 + N, 0xF, 0xF, true);
  union { int i; float f; } d; d.i = y;
  return d.f;
}
__device__ __forceinline__ float rowmax16(float v){
  v = fmaxf(v, ror16<1>(v));
  v = fmaxf(v, ror16<2>(v));
  v = fmaxf(v, ror16<4>(v));
  v = fmaxf(v, ror16<8>(v));
  return v;
}

#define GLB __attribute__((address_space(1)))
#define LDSAS __attribute__((address_space(3)))
__device__ __forceinline__ void async16(const void* g, void* l){
  __builtin_amdgcn_global_load_lds((const GLB u32*)g, (LDSAS u32*)l, 16, 0, 0);
}

#define LQ   1536
#define NPOS 3071   // 2L-1
#define NPOSP 3072  // row stride (row 3071 zeroed)

// ---------------------------------------------------------------------------
// pre_k: fused preprocessing, block-range dispatch (all parts independent).
//   blocks [0,2304):    x f32 -> bf16, 8 elems/thread, u16x8 store
//   blocks [2304,2784): weight transpose -> K-major bf16 (LDS tiled)
//   blocks [2784,3552): rK[h][k][d] for 4 k-rows/block; gamma max inline.
// ---------------------------------------------------------------------------
__global__ __launch_bounds__(256) void pre_k(
    const float* __restrict__ x,
    const float* __restrict__ Qw_, const float* __restrict__ Kw_,
    const float* __restrict__ Vw_, const float* __restrict__ Ow_,
    const float* __restrict__ relKw,
    u16* __restrict__ xb, u16* __restrict__ WtQKV, u16* __restrict__ WtOut,
    u16* __restrict__ rK)
{
  const int bx = blockIdx.x;
  const int t = threadIdx.x;

  if (bx < 2304) {
    // ---- cvt_x path: 8 elems/thread, one coalesced 16B store
    int gid = bx * 256 + t;
    float4 v0 = ((const float4*)x)[2*gid + 0];
    float4 v1 = ((const float4*)x)[2*gid + 1];
    u16x8_t ov;
    ov[0] = f2bf(v0.x); ov[1] = f2bf(v0.y); ov[2] = f2bf(v0.z); ov[3] = f2bf(v0.w);
    ov[4] = f2bf(v1.x); ov[5] = f2bf(v1.y); ov[6] = f2bf(v1.z); ov[7] = f2bf(v1.w);
    *(u16x8_t*)&xb[8*gid] = ov;
    return;
  }

  if (bx < 2784) {
    // ---- transpose_w path
    __shared__ u16 tile[64][65];
    int b2 = bx - 2304;
    const float* src; int stride, cl0, c0, k0; u16* dst;
    if (b2 < 336) {
      int ct = b2 % 28, kt = b2 / 28;
      c0 = ct*64; k0 = kt*64;
      if (c0 < 512)       { src = Qw_; stride = 512; cl0 = c0; }
      else if (c0 < 1024) { src = Kw_; stride = 512; cl0 = c0 - 512; }
      else                { src = Vw_; stride = 768; cl0 = c0 - 1024; }
      dst = WtQKV;
    } else {
      int b3 = b2 - 336; int ct = b3 % 12, kt = b3 / 12;
      c0 = ct*64; k0 = kt*64; src = Ow_; stride = 768; cl0 = c0; dst = WtOut;
    }
    #pragma unroll
    for (int e = 0; e < 16; ++e) {
      int idx = e*256 + t; int row = idx >> 6, col = idx & 63;
      tile[row][col] = f2bf(src[(size_t)(k0 + row)*stride + cl0 + col]);
    }
    __syncthreads();
    #pragma unroll
    for (int e = 0; e < 16; ++e) {
      int idx = e*256 + t; int orow = idx >> 6, ocol = idx & 63;
      dst[(size_t)(c0 + orow)*768 + k0 + ocol] = tile[ocol][orow];
    }
    return;
  }

  // ---- rk_k path: 4 k-rows per block
  __shared__ float gmaxs[16];
  __shared__ float feats[4][96];
  const int k0 = (bx - 2784) * 4;

  if (t < 16) {
    // gamma pdf unimodal in x; integer argmax at floor/ceil of mode.
    float fi   = (float)(t + 1);
    float conc = 4.0f * fi * fi;
    float rate = fi / 24.0f;
    float c1   = conc - 1.0f;
    float lognorm = lgammaf(conc) - conc * logf(rate);
    float mode = 96.0f*fi - 24.0f/fi;           // in [72, 1534.5] — interior
    float x1 = floorf(mode), x2 = x1 + 1.0f;
    if (x2 > 1535.0f) x2 = 1535.0f;
    float p1 = expf(c1*logf(x1) - rate*x1 - lognorm) + 1e-8f;
    float p2 = expf(c1*logf(x2) - rate*x2 - lognorm) + 1e-8f;
    gmaxs[t] = fmaxf(p1, p2);
  }
  __syncthreads();

  #pragma unroll
  for (int e = 0; e < 2; ++e) {
    int idx = e*256 + t;
    if (idx < 384) {
      int kl = idx / 96, f = idx - kl*96;
      int k = k0 + kl;
      float val = 0.0f;
      if (k != NPOS) {
        float pos = (float)(k - (LQ - 1));
        float xx  = fabsf(pos);
        float sgn = (float)((pos > 0.0f) - (pos < 0.0f));
        int fb = (f < 48) ? f : f - 48;
        float v;
        if (fb < 16) {
          float max_range = log2f((float)LQ);
          float hl = exp2f(3.0f + (float)fb * (max_range - 3.0f) / 15.0f);
          v = expf(-0.69314718056f / hl * xx);
        } else if (fb < 32) {
          int i = fb - 16;
          float width = (float)(1u << (i + 1)) - 1.0f;
          v = (width > xx) ? 1.0f : 0.0f;
        } else {
          int i = fb - 32;
          float fi   = (float)(i + 1);
          float conc = 4.0f * fi * fi;
          float rate = fi / 24.0f;
          float lognorm = lgammaf(conc) - conc * logf(rate);
          float lu = (xx == 0.0f) ? -INFINITY : ((conc - 1.0f) * logf(xx) - rate * xx);
          float p  = expf(lu - lognorm) + 1e-8f;
          v = p / gmaxs[i];
        }
        val = (f < 48) ? v : sgn * v;
      }
      feats[kl][f] = val;
    }
  }
  __syncthreads();

  #pragma unroll
  for (int ci = 0; ci < 2; ++ci) {
    int c = ci*256 + t;
    float a0 = 0.f, a1 = 0.f, a2 = 0.f, a3 = 0.f;
    #pragma unroll 4
    for (int f = 0; f < 96; ++f) {
      float wv = relKw[(size_t)f*512 + c];
      a0 += feats[0][f] * wv;
      a1 += feats[1][f] * wv;
      a2 += feats[2][f] * wv;
      a3 += feats[3][f] * wv;
    }
    size_t base = (((size_t)(c >> 6))*NPOSP + k0)*64 + (c & 63);
    rK[base +   0] = f2bf(a0);
    rK[base +  64] = f2bf(a1);
    rK[base + 128] = f2bf(a2);
    rK[base + 192] = f2bf(a3);
  }
}

// ---------------------------------------------------------------------------
// K4: fused QKV projection GEMM (M=6144, N=1792, K=768).
// 128x128 tile, 4 waves 2x2, 4x4 frags/wave (R17 measured win). grid (14,48).
// ---------------------------------------------------------------------------
__global__ __launch_bounds__(256) void qkv_gemm(
    const u16* __restrict__ xb, const u16* __restrict__ Wt,
    u16* __restrict__ Qb, u16* __restrict__ Kc, u16* __restrict__ Vt)
{
  const int n0 = blockIdx.x * 128;
  const int m0 = blockIdx.y * 128;
  const int tid = threadIdx.x, w = tid >> 6, lane = tid & 63, q = lane >> 4, s = lane & 15;
  const int wr = w >> 1, wc = w & 1;

  __shared__ __align__(16) u16 At[128*64];   // 16 KB
  __shared__ __align__(16) u16 Bt[128*64];   // 16 KB

  const char* ag = (const char*)(xb + (size_t)m0 * 768);
  const char* bg = (const char*)(Wt + (size_t)n0 * 768);

  const f32x4_t fz = {0.f, 0.f, 0.f, 0.f};
  f32x4_t acc[4][4];
  #pragma unroll
  for (int m = 0; m < 4; ++m)
    #pragma unroll
    for (int n = 0; n < 4; ++n) acc[m][n] = fz;

  for (int kk = 0; kk < 768; kk += 64) {
    #pragma unroll
    for (int c = 0; c < 4; ++c) {
      int ck = w*256 + c*64 + lane;                 // 1024 chunks each
      int grow = ck >> 3, gcol = (ck & 7) ^ (grow & 7);
      async16(ag + (size_t)grow*1536 + (size_t)(kk + gcol*8)*2, &At[(size_t)(w*256 + c*64)*8]);
      async16(bg + (size_t)grow*1536 + (size_t)(kk + gcol*8)*2, &Bt[(size_t)(w*256 + c*64)*8]);
    }
    __syncthreads();
    #pragma unroll
    for (int kf = 0; kf < 2; ++kf) {
      int sw = (kf*4 + q) ^ (s & 7);
      Frag af[4], bf[4];
      #pragma unroll
      for (int m = 0; m < 4; ++m)
        af[m].u = *(const u16x8_t*)&At[(size_t)((wr*64 + m*16 + s)*8 + sw)*8];
      #pragma unroll
      for (int n = 0; n < 4; ++n)
        bf[n].u = *(const u16x8_t*)&Bt[(size_t)((wc*64 + n*16 + s)*8 + sw)*8];
      #pragma unroll
      for (int m = 0; m < 4; ++m)
        #pragma unroll
        for (int n = 0; n < 4; ++n)
          acc[m][n] = __builtin_amdgcn_mfma_f32_16x16x32_bf16(af[m].b, bf[n].b, acc[m][n], 0, 0, 0);
    }
    __syncthreads();
  }

  #pragma unroll
  for (int m = 0; m < 4; ++m) {
    #pragma unroll
    for (int n = 0; n < 4; ++n) {
      int c = n0 + wc*64 + n*16 + s;
      #pragma unroll
      for (int r = 0; r < 4; ++r) {
        int row = m0 + wr*64 + m*16 + q*4 + r;
        int b = row / LQ, i = row - b*LQ;
        float v = acc[m][n][r];
        if (c < 512) {
          int h = c >> 6, d = c & 63;
          Qb[(((size_t)(b*8 + h))*LQ + i)*64 + d] = f2bf(v * 0.125f);
        } else if (c < 1024) {
          int cc = c - 512, h = cc >> 6, d = cc & 63;
          Kc[(((size_t)(b*8 + h))*LQ + i)*64 + d] = f2bf(v);
        } else {
          int cc = c - 1024, h = cc / 96, vv = cc - h*96;
          Vt[(((size_t)(b*8 + h))*96 + vv)*LQ + i] = f2bf(v);
        }
      }
    }
  }
}

// ---------------------------------------------------------------------------
// K5: fused attention, 512 threads (8 waves), i-tile 128.
// R24: K+V staged (8x reuse, bulk DMA), rK DIRECT from global (3.3x reuse,
// L2-hottest data). LDS 38KB (Kt 8 + Vs 12 + Ps 18) -> 4 blocks/CU.
// Per jt: [A] QK (Kt) + rel (rK direct) -> sync1 -> prefetch K(jt+1) ->
// [B] shift/softmax/PV (Vs) -> sync2 -> prefetch V(jt+1).
// ones-MFMA row-sum, DPP max. nz=4 j-split.
// ---------------------------------------------------------------------------
__global__ __launch_bounds__(512, 4) void attn_k(
    const u16* __restrict__ Qb, const u16* __restrict__ Kc,
    const u16* __restrict__ Vt, const u16* __restrict__ rK,
    const float* __restrict__ rwb, const float* __restrict__ rrb,
    u16* __restrict__ attnO, u16* __restrict__ Opart, float* __restrict__ ml,
    int nz)
{
  const int n = blockIdx.x;
  const int bpb = 12 * nz;
  const int slot = n >> 3;
  const int bh = (n & 7) * 4 + slot / bpb;
  const int rm = slot % bpb;
  const int it = rm % 12, z = rm / 12;
  const int i0 = it * 128;
  const int b = bh >> 3, h = bh & 7;
  const int tid = threadIdx.x;
  const int w = tid >> 6, lane = tid & 63, q = lane >> 4, s = lane & 15;

  __shared__ __align__(16) u16 Kt[64*64];       // 8 KB
  __shared__ __align__(16) u16 Vs[96*64];       // 12 KB
  __shared__ __align__(16) u16 Ps[8][16][72];   // 18 KB   (total 38 KB)

  // Q fragments with biases folded
  Frag qwf[2], qrf[2];
  {
    const u16* qb = Qb + (((size_t)bh)*LQ + i0 + 16*w + s)*64;
    #pragma unroll
    for (int kf = 0; kf < 2; ++kf) {
      u16x8_t qraw = *(const u16x8_t*)(qb + kf*32 + q*8);
      #pragma unroll
      for (int j = 0; j < 8; ++j) {
        int d = kf*32 + q*8 + j;
        float qv = bf2f(qraw[j]);
        qwf[kf].u[j] = f2bf_hw(qv + rwb[h*64 + d]);
        qrf[kf].u[j] = f2bf_hw(qv + rrb[h*64 + d]);
      }
    }
  }

  Frag ones;
  #pragma unroll
  for (int j = 0; j < 8; ++j) ones.u[j] = 0x3F80;   // bf16 1.0

  const f32x4_t fz = {0.f, 0.f, 0.f, 0.f};
  float mrun[4];
  f32x4_t acco[6], accl;
  #pragma unroll
  for (int r = 0; r < 4; ++r) mrun[r] = -1e30f;
  #pragma unroll
  for (int vs = 0; vs < 6; ++vs) acco[vs] = fz;
  accl = fz;

  const char* kcb = (const char*)(Kc + ((size_t)bh)*LQ*64);
  const char* vtb = (const char*)(Vt + ((size_t)bh)*96*LQ);
  const u16*  rkb = rK + (size_t)h*NPOSP*64;

  const int swz0 = (0*4 + q) ^ (s & 7);
  const int swz1 = (1*4 + q) ^ (s & 7);

  const int njt = 24 / nz;
  const int jt0 = z * njt;
  const int jtend = jt0 + njt;

  // ---- staging helpers (global src pre-swizzled, LDS dest linear) ----
  auto stageK = [&](int jtS) {
    const char* kg = kcb + (size_t)(jtS*64) * 128;
    int ck = tid;
    int grow = ck >> 3, gcol = (ck & 7) ^ (grow & 7);
    async16(kg + (size_t)grow*128 + gcol*16, &Kt[(size_t)(w*64)*8]);
  };
  auto stageV = [&](int jtS) {
    const char* vg = vtb + (size_t)(jtS*64) * 2;
    {
      int ck = tid;
      int grow = ck >> 3, gcol = (ck & 7) ^ (grow & 7);
      async16(vg + (size_t)grow*(LQ*2) + gcol*16, &Vs[(size_t)(w*64)*8]);
    }
    if (tid < 256) {
      int ck = 512 + tid;
      int grow = ck >> 3, gcol = (ck & 7) ^ (grow & 7);
      async16(vg + (size_t)grow*(LQ*2) + gcol*16, &Vs[(size_t)(512 + w*64)*8]);
    }
  };

  // ---- prologue: K(jt0), V(jt0); drain once
  stageK(jt0);
  stageV(jt0);
  __syncthreads();

  for (int jt = jt0; jt < jtend; ++jt) {
    const int k0 = jt*64 - i0 + (LQ - 128);   // band base (>=0; max row 3071)

    // ---- [A] content (Kt staged) + rel (rK direct, L2-hot) scores
    f32x4_t accc[4] = {fz, fz, fz, fz};
    f32x4_t accr[5] = {fz, fz, fz, fz, fz};
    // rel loads: addresses independent of Kt -> issue early, overlap with
    // content MFMAs; 5 independent accr chains absorb L2 latency.
    Frag rb0[5], rb1[5];
    #pragma unroll
    for (int nn = 0; nn < 5; ++nn) {
      int ar = k0 + (7 - w + nn)*16 + s;      // absolute band row <= 3071
      const u16* rr = rkb + (size_t)ar*64 + q*8;
      rb0[nn].u = *(const u16x8_t*)(rr);
      rb1[nn].u = *(const u16x8_t*)(rr + 32);
    }
    #pragma unroll
    for (int ns = 0; ns < 4; ++ns) {
      int row = ns*16 + s;
      Frag b0; b0.u = *(const u16x8_t*)&Kt[(size_t)(row*8 + swz0)*8];
      Frag b1; b1.u = *(const u16x8_t*)&Kt[(size_t)(row*8 + swz1)*8];
      accc[ns] = __builtin_amdgcn_mfma_f32_16x16x32_bf16(qwf[0].b, b0.b, accc[ns], 0, 0, 0);
      accc[ns] = __builtin_amdgcn_mfma_f32_16x16x32_bf16(qwf[1].b, b1.b, accc[ns], 0, 0, 0);
    }
    #pragma unroll
    for (int nn = 0; nn < 5; ++nn) {
      accr[nn] = __builtin_amdgcn_mfma_f32_16x16x32_bf16(qrf[0].b, rb0[nn].b, accr[nn], 0, 0, 0);
      accr[nn] = __builtin_amdgcn_mfma_f32_16x16x32_bf16(qrf[1].b, rb1[nn].b, accr[nn], 0, 0, 0);
    }

    // sync1: all waves done reading Kt; drains V(jt) DMA
    __syncthreads();

    // ---- prefetch K(jt+1) (hides under [B])
    if (jt + 1 < jtend) stageK(jt + 1);

    // ---- [B] diagonal shift via bpermute (w-terms cancel)
    #pragma unroll
    for (int r = 0; r < 4; ++r) {
      int tt = s + 15 - 4*q - r;               // [0,30]
      int srcl = (lane & 48) | (tt & 15);
      bool hi = tt >= 16;
      float v[5];
      #pragma unroll
      for (int nn = 0; nn < 5; ++nn) v[nn] = __shfl(accr[nn][r], srcl, 64);
      #pragma unroll
      for (int ns = 0; ns < 4; ++ns)
        accc[ns][r] += hi ? v[ns + 1] : v[ns];
    }

    // ---- [B] online softmax (DPP max; sum via ones-MFMA)
    #pragma unroll
    for (int r = 0; r < 4; ++r) {
      float mx = fmaxf(fmaxf(accc[0][r], accc[1][r]), fmaxf(accc[2][r], accc[3][r]));
      mx = rowmax16(mx);
      float mnew  = fmaxf(mrun[r], mx);
      float alpha = __expf(mrun[r] - mnew);
      #pragma unroll
      for (int ns = 0; ns < 4; ++ns)
        accc[ns][r] = __expf(accc[ns][r] - mnew);
      mrun[r] = mnew;
      accl[r] *= alpha;
      #pragma unroll
      for (int vs = 0; vs < 6; ++vs) acco[vs][r] *= alpha;
    }

    // ---- [B] P: C-layout -> per-wave LDS -> A-layout
    #pragma unroll
    for (int ns = 0; ns < 4; ++ns)
      #pragma unroll
      for (int r = 0; r < 4; ++r)
        Ps[w][q*4 + r][ns*16 + s] = f2bf_hw(accc[ns][r]);

    // ---- [B] PV + ones-column row-sum (Vs staged)
    #pragma unroll
    for (int kf = 0; kf < 2; ++kf) {
      Frag pf; pf.u = *(const u16x8_t*)(&Ps[w][s][kf*32 + q*8]);
      int sw = kf ? swz1 : swz0;
      #pragma unroll
      for (int vs = 0; vs < 6; ++vs) {
        int row = vs*16 + s;
        Frag vf; vf.u = *(const u16x8_t*)&Vs[(size_t)(row*8 + sw)*8];
        acco[vs] = __builtin_amdgcn_mfma_f32_16x16x32_bf16(pf.b, vf.b, acco[vs], 0, 0, 0);
      }
      accl = __builtin_amdgcn_mfma_f32_16x16x32_bf16(pf.b, ones.b, accl, 0, 0, 0);
    }

    // sync2: all waves done reading Vs/Ps; drains K DMA
    __syncthreads();

    // ---- prefetch V(jt+1) (hides under next [A])
    if (jt + 1 < jtend) stageV(jt + 1);
  }

  // ---- epilogue
  if (nz == 1) {
    #pragma unroll
    for (int r = 0; r < 4; ++r) {
      float inv = frcp(accl[r]);
      int i = i0 + 16*w + q*4 + r;
      #pragma unroll
      for (int vs = 0; vs < 6; ++vs) {
        int v = vs*16 + s;
        attnO[((size_t)b*LQ + i)*768 + h*96 + v] = f2bf_hw(acco[vs][r] * inv);
      }
    }
  } else {
    #pragma unroll
    for (int vs = 0; vs < 6; ++vs) {
      int v = vs*16 + s;
      #pragma unroll
      for (int r = 0; r < 4; ++r) {
        int i = i0 + 16*w + q*4 + r;
        size_t rg = (size_t)(z*32 + bh)*LQ + i;
        Opart[rg*96 + v] = f2bf_hw(acco[vs][r]);
      }
    }
    if (s == 0) {
      #pragma unroll
      for (int r = 0; r < 4; ++r) {
        int i = i0 + 16*w + q*4 + r;
        size_t rg = (size_t)(z*32 + bh)*LQ + i;
        ml[rg*2 + 0] = mrun[r];
        ml[rg*2 + 1] = accl[r];
      }
    }
  }
}

// ---------------------------------------------------------------------------
// K5b: flash combine of nz j-partials -> attnO bf16.
// Vectorized u16x8 (8 v-elems/thread), grid 2304 x 256.
// ---------------------------------------------------------------------------
__global__ void combine_k(const u16* __restrict__ Opart, const float* __restrict__ ml,
                          u16* __restrict__ attnO, int nz)
{
  int g = blockIdx.x * 256 + threadIdx.x;     // one (row, 8-v-group) per thread
  if (g >= 32*LQ*12) return;
  int vg = g % 12, row = g / 12;
  int v0 = vg * 8;
  int bh = row / LQ, i = row - bh*LQ;
  int b = bh >> 3, h = bh & 7;
  float M = -1e30f;
  for (int z = 0; z < nz; ++z)
    M = fmaxf(M, ml[((size_t)(z*32 + bh)*LQ + i)*2]);
  float L = 0.f;
  float num[8];
  #pragma unroll
  for (int j = 0; j < 8; ++j) num[j] = 0.f;
  for (int z = 0; z < nz; ++z) {
    size_t rg = (size_t)(z*32 + bh)*LQ + i;
    float e = __expf(ml[rg*2] - M);
    L += ml[rg*2 + 1] * e;
    u16x8_t ov = *(const u16x8_t*)&Opart[rg*96 + v0];
    #pragma unroll
    for (int j = 0; j < 8; ++j) num[j] += bf2f(ov[j]) * e;
  }
  float invL = frcp(L);
  u16x8_t outv;
  #pragma unroll
  for (int j = 0; j < 8; ++j) outv[j] = f2bf(num[j] * invL);
  *(u16x8_t*)&attnO[((size_t)b*LQ + i)*768 + h*96 + v0] = outv;
}

// ---------------------------------------------------------------------------
// K6: output projection (M=6144, N=768, K=768) + bias -> d_out FLOAT.
// 64x64 tile. grid (12,96).
// ---------------------------------------------------------------------------
__global__ __launch_bounds__(256) void out_gemm(
    const u16* __restrict__ A, const u16* __restrict__ Wt,
    const float* __restrict__ bias, float* __restrict__ out)
{
  const int n0 = blockIdx.x * 64;
  const int m0 = blockIdx.y * 64;
  const int tid = threadIdx.x, w = tid >> 6, lane = tid & 63, q = lane >> 4, s = lane & 15;

  __shared__ __align__(16) u16 At[64*64];
  __shared__ __align__(16) u16 Bt[64*64];

  const char* ag = (const char*)(A  + (size_t)m0 * 768);
  const char* bg = (const char*)(Wt + (size_t)n0 * 768);

  const f32x4_t fz = {0.f, 0.f, 0.f, 0.f};
  f32x4_t acc[4] = {fz, fz, fz, fz};

  for (int kk = 0; kk < 768; kk += 64) {
    #pragma unroll
    for (int c = 0; c < 2; ++c) {
      int ck = w*128 + c*64 + lane;
      int grow = ck >> 3, gcol = (ck & 7) ^ (grow & 7);
      async16(ag + (size_t)grow*1536 + (size_t)(kk + gcol*8)*2, &At[(size_t)(w*128 + c*64)*8]);
      async16(bg + (size_t)grow*1536 + (size_t)(kk + gcol*8)*2, &Bt[(size_t)(w*128 + c*64)*8]);
    }
    __syncthreads();
    #pragma unroll
    for (int kf = 0; kf < 2; ++kf) {
      int sw = (kf*4 + q) ^ (s & 7);
      Frag af; af.u = *(const u16x8_t*)&At[(size_t)((16*w + s)*8 + sw)*8];
      #pragma unroll
      for (int ns = 0; ns < 4; ++ns) {
        Frag bf; bf.u = *(const u16x8_t*)&Bt[(size_t)((ns*16 + s)*8 + sw)*8];
        acc[ns] = __builtin_amdgcn_mfma_f32_16x16x32_bf16(af.b, bf.b, acc[ns], 0, 0, 0);
      }
    }
    __syncthreads();
  }

  #pragma unroll
  for (int ns = 0; ns < 4; ++ns) {
    int c = n0 + ns*16 + s;
    float bv = bias[c];
    #pragma unroll
    for (int r = 0; r < 4; ++r) {
      int row = m0 + 16*w + q*4 + r;
      out[(size_t)row*768 + c] = acc[ns][r] + bv;
    }
  }
}

// ---------------------------------------------------------------------------
extern "C" void kernel_launch(void* const* d_in, const int* in_sizes, int n_in,
                              void* d_out, int out_size, void* d_ws, size_t ws_size,
                              hipStream_t stream)
{
  (void)out_size;

  static const int dict_sig[9] = {4718592,393216,393216,589824,589824,768,49152,512,512};
  bool is_dict = (n_in == 9);
  for (int i = 0; i < 9 && i < n_in; ++i)
    if (in_sizes[i] != dict_sig[i]) is_dict = false;

  const float *x, *Qw_w, *Kw_w, *Vw_w, *Ow_w, *out_b, *relKw, *rwb, *rrb;
  if (is_dict) {
    x     = (const float*)d_in[0];  Qw_w  = (const float*)d_in[1];
    Kw_w  = (const float*)d_in[2];  Vw_w  = (const float*)d_in[3];
    Ow_w  = (const float*)d_in[4];  out_b = (const float*)d_in[5];
    relKw = (const float*)d_in[6];  rwb   = (const float*)d_in[7];
    rrb   = (const float*)d_in[8];
  } else {
    const float* p393[2] = {nullptr,nullptr}; int n393 = 0;
    const float* p589[2] = {nullptr,nullptr}; int n589 = 0;
    const float* p512[2] = {nullptr,nullptr}; int n512 = 0;
    const float *px = nullptr, *prel = nullptr, *pb = nullptr;
    for (int i = 0; i < n_in; ++i) {
      const float* p = (const float*)d_in[i];
      switch (in_sizes[i]) {
        case 4718592: px = p; break;
        case 49152:   prel = p; break;
        case 768:     pb = p; break;
        case 393216:  if (n393 < 2) p393[n393++] = p; break;
        case 589824:  if (n589 < 2) p589[n589++] = p; break;
        case 512:     if (n512 < 2) p512[n512++] = p; break;
        default: break;
      }
    }
    x = px; relKw = prel; out_b = pb;
    Qw_w = p393[0]; Kw_w = p393[1];
    Vw_w = p589[0]; Ow_w = p589[1];
    rwb  = p512[0]; rrb  = p512[1];
  }

  float* out = (float*)d_out;

  char* ws = (char*)d_ws;
  size_t off = 0;
  auto alloc = [&](size_t bytes) -> void* {
    void* p = ws + off;
    off += (bytes + 255) & ~(size_t)255;
    return p;
  };

  u16*   WtQKV = (u16*)  alloc((size_t)1792*768*2);   // 2.75 MB
  u16*   WtOut = (u16*)  alloc((size_t)768*768*2);    // 1.18 MB
  u16*   rK    = (u16*)  alloc((size_t)8*NPOSP*64*2); // 3 MB
  u16*   Qb    = (u16*)  alloc((size_t)32*LQ*64*2);   // 6.3 MB
  u16*   Kc    = (u16*)  alloc((size_t)32*LQ*64*2);   // 6.3 MB
  u16*   Vt    = (u16*)  alloc((size_t)32*96*LQ*2);   // 9.4 MB
  u16*   xb    = (u16*)  alloc((size_t)6144*768*2);   // 9.4 MB
  u16*   attnO = xb;  // alias: xb dead after qkv_gemm

  // pick nz by workspace headroom (partials = nz*(9.44 MB + 0.39 MB))
  size_t base_off = off;
  auto need = [&](int nzv) -> size_t {
    size_t o = base_off;
    o += (((size_t)nzv*32*LQ*96*2) + 255) & ~(size_t)255;
    o += (((size_t)nzv*32*LQ*2*4) + 255) & ~(size_t)255;
    return o;
  };
  int nz = 1;
  if (ws_size >= need(4)) nz = 4;
  else if (ws_size >= need(2)) nz = 2;
  u16*   Opart = nullptr; float* ml = nullptr;
  if (nz > 1) {
    Opart = (u16*)  alloc((size_t)nz*32*LQ*96*2);
    ml    = (float*)alloc((size_t)nz*32*LQ*2*4);
  }

  pre_k      <<<dim3(3552), dim3(256), 0, stream>>>(x, Qw_w, Kw_w, Vw_w, Ow_w,
                                                    relKw, xb, WtQKV, WtOut, rK);
  qkv_gemm   <<<dim3(14,48),dim3(256), 0, stream>>>(xb, WtQKV, Qb, Kc, Vt);
  attn_k     <<<dim3(384*nz),dim3(512), 0, stream>>>(Qb, Kc, Vt, rK, rwb, rrb,
                                                     attnO, Opart, ml, nz);
  if (nz > 1)
    combine_k<<<dim3(2304),  dim3(256), 0, stream>>>(Opart, ml, attnO, nz);
  out_gemm   <<<dim3(12,96),dim3(256), 0, stream>>>(attnO, WtOut, out_b, out);
}

// Round 15
// 299.975 us; speedup vs baseline: 1.1535x; 1.1535x over previous
//
#include <hip/hip_runtime.h>

// ---------------------------------------------------------------------------
// MHSelfAttention (Transformer-XL relative shift), MI355X gfx950
// B=4 L=1536 D=768 H=8 DQK=64 DV=96 NPF=96
// logits[b,h,i,j] = (Q*s+rwb)[i].K[j] + (Q*s+rrb)[i].rK[j-i+L-1]
// R25: FINAL — restore best-measured configuration (R23; 315-319us across
// 3 runs). Staging ablation complete: all-staged 147 < rK-direct 181 <
// none 285 us — bulk global_load_lds staging strictly dominant for MFMA
// operands with >=3x intra-block reuse (per-lane L2 loads serialize ~200cy
// on operand chains; TLP gains don't compensate). attn_k: 8-wave i-tile-128,
// rK ring + split-phase prefetch + ones-MFMA row-sum + DPP rowmax.
// Satellites (each single-variable verified): pre_k fused w/ analytic gamma
// max + vectorized cvt, qkv 128x128, out 64x64, combine u16x8.
// ---------------------------------------------------------------------------

typedef unsigned short u16;
typedef unsigned int   u32;

typedef __bf16 bf16x8_t __attribute__((ext_vector_type(8)));
typedef unsigned short u16x8_t __attribute__((ext_vector_type(8)));
typedef float f32x4_t __attribute__((ext_vector_type(4)));

union Frag { u16x8_t u; bf16x8_t b; };

__device__ __forceinline__ float bf2f(u16 v){
  union { u32 i; float f; } c; c.i = ((u32)v) << 16; return c.f;
}
__device__ __forceinline__ u16 f2bf(float f){
  union { float f; u32 i; } c; c.f = f;
  u32 r = c.i + 0x7FFFu + ((c.i >> 16) & 1u);
  return (u16)(r >> 16);
}
// HW RNE cast — 1 op vs 4-op manual f2bf
__device__ __forceinline__ u16 f2bf_hw(float f){
  __bf16 h = (__bf16)f;
  union { __bf16 h; u16 u; } c; c.h = h; return c.u;
}
__device__ __forceinline__ float frcp(float x){
#if __has_builtin(__builtin_amdgcn_rcpf)
  return __builtin_amdgcn_rcpf(x);
#else
  return 1.0f / x;
#endif
}

// DPP row_ror:N within 16-lane rows (VALU, no DS pipe).
template<int N>
__device__ __forceinline__ float ror16(float x){
  union { float f; int i; } c; c.f = x;
  int y = __builtin_amdgcn_update_dpp(0, c.i, 0x120 + N, 0xF, 0xF, true);
  union { int i; float f; } d; d.i = y;
  return d.f;
}
__device__ __forceinline__ float rowmax16(float v){
  v = fmaxf(v, ror16<1>(v));
  v = fmaxf(v, ror16<2>(v));
  v = fmaxf(v, ror16<4>(v));
  v = fmaxf(v, ror16<8>(v));
  return v;
}

#define GLB __attribute__((address_space(1)))
#define LDSAS __attribute__((address_space(3)))
__device__ __forceinline__ void async16(const void* g, void* l){
  __builtin_amdgcn_global_load_lds((const GLB u32*)g, (LDSAS u32*)l, 16, 0, 0);
}

#define LQ   1536
#define NPOS 3071   // 2L-1
#define NPOSP 3072  // row stride (row 3071 zeroed)

// ---------------------------------------------------------------------------
// pre_k: fused preprocessing, block-range dispatch (all parts independent).
//   blocks [0,2304):    x f32 -> bf16, 8 elems/thread, u16x8 store
//   blocks [2304,2784): weight transpose -> K-major bf16 (LDS tiled)
//   blocks [2784,3552): rK[h][k][d] for 4 k-rows/block; gamma max inline.
// ---------------------------------------------------------------------------
__global__ __launch_bounds__(256) void pre_k(
    const float* __restrict__ x,
    const float* __restrict__ Qw_, const float* __restrict__ Kw_,
    const float* __restrict__ Vw_, const float* __restrict__ Ow_,
    const float* __restrict__ relKw,
    u16* __restrict__ xb, u16* __restrict__ WtQKV, u16* __restrict__ WtOut,
    u16* __restrict__ rK)
{
  const int bx = blockIdx.x;
  const int t = threadIdx.x;

  if (bx < 2304) {
    // ---- cvt_x path: 8 elems/thread, one coalesced 16B store
    int gid = bx * 256 + t;
    float4 v0 = ((const float4*)x)[2*gid + 0];
    float4 v1 = ((const float4*)x)[2*gid + 1];
    u16x8_t ov;
    ov[0] = f2bf(v0.x); ov[1] = f2bf(v0.y); ov[2] = f2bf(v0.z); ov[3] = f2bf(v0.w);
    ov[4] = f2bf(v1.x); ov[5] = f2bf(v1.y); ov[6] = f2bf(v1.z); ov[7] = f2bf(v1.w);
    *(u16x8_t*)&xb[8*gid] = ov;
    return;
  }

  if (bx < 2784) {
    // ---- transpose_w path
    __shared__ u16 tile[64][65];
    int b2 = bx - 2304;
    const float* src; int stride, cl0, c0, k0; u16* dst;
    if (b2 < 336) {
      int ct = b2 % 28, kt = b2 / 28;
      c0 = ct*64; k0 = kt*64;
      if (c0 < 512)       { src = Qw_; stride = 512; cl0 = c0; }
      else if (c0 < 1024) { src = Kw_; stride = 512; cl0 = c0 - 512; }
      else                { src = Vw_; stride = 768; cl0 = c0 - 1024; }
      dst = WtQKV;
    } else {
      int b3 = b2 - 336; int ct = b3 % 12, kt = b3 / 12;
      c0 = ct*64; k0 = kt*64; src = Ow_; stride = 768; cl0 = c0; dst = WtOut;
    }
    #pragma unroll
    for (int e = 0; e < 16; ++e) {
      int idx = e*256 + t; int row = idx >> 6, col = idx & 63;
      tile[row][col] = f2bf(src[(size_t)(k0 + row)*stride + cl0 + col]);
    }
    __syncthreads();
    #pragma unroll
    for (int e = 0; e < 16; ++e) {
      int idx = e*256 + t; int orow = idx >> 6, ocol = idx & 63;
      dst[(size_t)(c0 + orow)*768 + k0 + ocol] = tile[ocol][orow];
    }
    return;
  }

  // ---- rk_k path: 4 k-rows per block
  __shared__ float gmaxs[16];
  __shared__ float feats[4][96];
  const int k0 = (bx - 2784) * 4;

  if (t < 16) {
    // gamma pdf unimodal in x; integer argmax at floor/ceil of mode.
    float fi   = (float)(t + 1);
    float conc = 4.0f * fi * fi;
    float rate = fi / 24.0f;
    float c1   = conc - 1.0f;
    float lognorm = lgammaf(conc) - conc * logf(rate);
    float mode = 96.0f*fi - 24.0f/fi;           // in [72, 1534.5] — interior
    float x1 = floorf(mode), x2 = x1 + 1.0f;
    if (x2 > 1535.0f) x2 = 1535.0f;
    float p1 = expf(c1*logf(x1) - rate*x1 - lognorm) + 1e-8f;
    float p2 = expf(c1*logf(x2) - rate*x2 - lognorm) + 1e-8f;
    gmaxs[t] = fmaxf(p1, p2);
  }
  __syncthreads();

  #pragma unroll
  for (int e = 0; e < 2; ++e) {
    int idx = e*256 + t;
    if (idx < 384) {
      int kl = idx / 96, f = idx - kl*96;
      int k = k0 + kl;
      float val = 0.0f;
      if (k != NPOS) {
        float pos = (float)(k - (LQ - 1));
        float xx  = fabsf(pos);
        float sgn = (float)((pos > 0.0f) - (pos < 0.0f));
        int fb = (f < 48) ? f : f - 48;
        float v;
        if (fb < 16) {
          float max_range = log2f((float)LQ);
          float hl = exp2f(3.0f + (float)fb * (max_range - 3.0f) / 15.0f);
          v = expf(-0.69314718056f / hl * xx);
        } else if (fb < 32) {
          int i = fb - 16;
          float width = (float)(1u << (i + 1)) - 1.0f;
          v = (width > xx) ? 1.0f : 0.0f;
        } else {
          int i = fb - 32;
          float fi   = (float)(i + 1);
          float conc = 4.0f * fi * fi;
          float rate = fi / 24.0f;
          float lognorm = lgammaf(conc) - conc * logf(rate);
          float lu = (xx == 0.0f) ? -INFINITY : ((conc - 1.0f) * logf(xx) - rate * xx);
          float p  = expf(lu - lognorm) + 1e-8f;
          v = p / gmaxs[i];
        }
        val = (f < 48) ? v : sgn * v;
      }
      feats[kl][f] = val;
    }
  }
  __syncthreads();

  #pragma unroll
  for (int ci = 0; ci < 2; ++ci) {
    int c = ci*256 + t;
    float a0 = 0.f, a1 = 0.f, a2 = 0.f, a3 = 0.f;
    #pragma unroll 4
    for (int f = 0; f < 96; ++f) {
      float wv = relKw[(size_t)f*512 + c];
      a0 += feats[0][f] * wv;
      a1 += feats[1][f] * wv;
      a2 += feats[2][f] * wv;
      a3 += feats[3][f] * wv;
    }
    size_t base = (((size_t)(c >> 6))*NPOSP + k0)*64 + (c & 63);
    rK[base +   0] = f2bf(a0);
    rK[base +  64] = f2bf(a1);
    rK[base + 128] = f2bf(a2);
    rK[base + 192] = f2bf(a3);
  }
}

// ---------------------------------------------------------------------------
// K4: fused QKV projection GEMM (M=6144, N=1792, K=768).
// 128x128 tile, 4 waves 2x2, 4x4 frags/wave (R17 measured win). grid (14,48).
// ---------------------------------------------------------------------------
__global__ __launch_bounds__(256) void qkv_gemm(
    const u16* __restrict__ xb, const u16* __restrict__ Wt,
    u16* __restrict__ Qb, u16* __restrict__ Kc, u16* __restrict__ Vt)
{
  const int n0 = blockIdx.x * 128;
  const int m0 = blockIdx.y * 128;
  const int tid = threadIdx.x, w = tid >> 6, lane = tid & 63, q = lane >> 4, s = lane & 15;
  const int wr = w >> 1, wc = w & 1;

  __shared__ __align__(16) u16 At[128*64];   // 16 KB
  __shared__ __align__(16) u16 Bt[128*64];   // 16 KB

  const char* ag = (const char*)(xb + (size_t)m0 * 768);
  const char* bg = (const char*)(Wt + (size_t)n0 * 768);

  const f32x4_t fz = {0.f, 0.f, 0.f, 0.f};
  f32x4_t acc[4][4];
  #pragma unroll
  for (int m = 0; m < 4; ++m)
    #pragma unroll
    for (int n = 0; n < 4; ++n) acc[m][n] = fz;

  for (int kk = 0; kk < 768; kk += 64) {
    #pragma unroll
    for (int c = 0; c < 4; ++c) {
      int ck = w*256 + c*64 + lane;                 // 1024 chunks each
      int grow = ck >> 3, gcol = (ck & 7) ^ (grow & 7);
      async16(ag + (size_t)grow*1536 + (size_t)(kk + gcol*8)*2, &At[(size_t)(w*256 + c*64)*8]);
      async16(bg + (size_t)grow*1536 + (size_t)(kk + gcol*8)*2, &Bt[(size_t)(w*256 + c*64)*8]);
    }
    __syncthreads();
    #pragma unroll
    for (int kf = 0; kf < 2; ++kf) {
      int sw = (kf*4 + q) ^ (s & 7);
      Frag af[4], bf[4];
      #pragma unroll
      for (int m = 0; m < 4; ++m)
        af[m].u = *(const u16x8_t*)&At[(size_t)((wr*64 + m*16 + s)*8 + sw)*8];
      #pragma unroll
      for (int n = 0; n < 4; ++n)
        bf[n].u = *(const u16x8_t*)&Bt[(size_t)((wc*64 + n*16 + s)*8 + sw)*8];
      #pragma unroll
      for (int m = 0; m < 4; ++m)
        #pragma unroll
        for (int n = 0; n < 4; ++n)
          acc[m][n] = __builtin_amdgcn_mfma_f32_16x16x32_bf16(af[m].b, bf[n].b, acc[m][n], 0, 0, 0);
    }
    __syncthreads();
  }

  #pragma unroll
  for (int m = 0; m < 4; ++m) {
    #pragma unroll
    for (int n = 0; n < 4; ++n) {
      int c = n0 + wc*64 + n*16 + s;
      #pragma unroll
      for (int r = 0; r < 4; ++r) {
        int row = m0 + wr*64 + m*16 + q*4 + r;
        int b = row / LQ, i = row - b*LQ;
        float v = acc[m][n][r];
        if (c < 512) {
          int h = c >> 6, d = c & 63;
          Qb[(((size_t)(b*8 + h))*LQ + i)*64 + d] = f2bf(v * 0.125f);
        } else if (c < 1024) {
          int cc = c - 512, h = cc >> 6, d = cc & 63;
          Kc[(((size_t)(b*8 + h))*LQ + i)*64 + d] = f2bf(v);
        } else {
          int cc = c - 1024, h = cc / 96, vv = cc - h*96;
          Vt[(((size_t)(b*8 + h))*96 + vv)*LQ + i] = f2bf(v);
        }
      }
    }
  }
}

// ---------------------------------------------------------------------------
// K5: fused attention, 512 threads (8 waves), i-tile 128.  (best-measured)
// LDS 70KB (2 blocks/CU): Kt 8KB, Rt 256-row ring 32KB, Vs 12KB, Ps 18KB.
// Per jt: [A] QK+rel MFMA -> sync1 -> prefetch K/rK(jt+1) -> [B] shift/
// softmax/PV -> sync2 -> prefetch V(jt+1). ones-MFMA row-sum, DPP max.
// ---------------------------------------------------------------------------
__global__ __launch_bounds__(512, 4) void attn_k(
    const u16* __restrict__ Qb, const u16* __restrict__ Kc,
    const u16* __restrict__ Vt, const u16* __restrict__ rK,
    const float* __restrict__ rwb, const float* __restrict__ rrb,
    u16* __restrict__ attnO, u16* __restrict__ Opart, float* __restrict__ ml,
    int nz)
{
  const int n = blockIdx.x;
  const int bpb = 12 * nz;
  const int slot = n >> 3;
  const int bh = (n & 7) * 4 + slot / bpb;
  const int rm = slot % bpb;
  const int it = rm % 12, z = rm / 12;
  const int i0 = it * 128;
  const int b = bh >> 3, h = bh & 7;
  const int tid = threadIdx.x;
  const int w = tid >> 6, lane = tid & 63, q = lane >> 4, s = lane & 15;

  __shared__ __align__(16) u16 Kt[64*64];       // 8 KB
  __shared__ __align__(16) u16 Rt[256*64];      // 32 KB ring (abs row & 255)
  __shared__ __align__(16) u16 Vs[96*64];       // 12 KB
  __shared__ __align__(16) u16 Ps[8][16][72];   // 18 KB   (total 70 KB)

  // Q fragments with biases folded
  Frag qwf[2], qrf[2];
  {
    const u16* qb = Qb + (((size_t)bh)*LQ + i0 + 16*w + s)*64;
    #pragma unroll
    for (int kf = 0; kf < 2; ++kf) {
      u16x8_t qraw = *(const u16x8_t*)(qb + kf*32 + q*8);
      #pragma unroll
      for (int j = 0; j < 8; ++j) {
        int d = kf*32 + q*8 + j;
        float qv = bf2f(qraw[j]);
        qwf[kf].u[j] = f2bf_hw(qv + rwb[h*64 + d]);
        qrf[kf].u[j] = f2bf_hw(qv + rrb[h*64 + d]);
      }
    }
  }

  Frag ones;
  #pragma unroll
  for (int j = 0; j < 8; ++j) ones.u[j] = 0x3F80;   // bf16 1.0

  const f32x4_t fz = {0.f, 0.f, 0.f, 0.f};
  float mrun[4];
  f32x4_t acco[6], accl;
  #pragma unroll
  for (int r = 0; r < 4; ++r) mrun[r] = -1e30f;
  #pragma unroll
  for (int vs = 0; vs < 6; ++vs) acco[vs] = fz;
  accl = fz;

  const char* kcb = (const char*)(Kc + ((size_t)bh)*LQ*64);
  const char* vtb = (const char*)(Vt + ((size_t)bh)*96*LQ);
  const char* rkb = (const char*)(rK + ((size_t)h)*NPOSP*64);

  const int swz0 = (0*4 + q) ^ (s & 7);
  const int swz1 = (1*4 + q) ^ (s & 7);

  const int njt = 24 / nz;
  const int jt0 = z * njt;
  const int jtend = jt0 + njt;

  // ---- staging helpers (global src pre-swizzled, LDS dest linear) ----
  auto stageK = [&](int jtS) {
    const char* kg = kcb + (size_t)(jtS*64) * 128;
    int ck = tid;
    int grow = ck >> 3, gcol = (ck & 7) ^ (grow & 7);
    async16(kg + (size_t)grow*128 + gcol*16, &Kt[(size_t)(w*64)*8]);
  };
  auto stageV = [&](int jtS) {
    const char* vg = vtb + (size_t)(jtS*64) * 2;
    {
      int ck = tid;
      int grow = ck >> 3, gcol = (ck & 7) ^ (grow & 7);
      async16(vg + (size_t)grow*(LQ*2) + gcol*16, &Vs[(size_t)(w*64)*8]);
    }
    if (tid < 256) {
      int ck = 512 + tid;
      int grow = ck >> 3, gcol = (ck & 7) ^ (grow & 7);
      async16(vg + (size_t)grow*(LQ*2) + gcol*16, &Vs[(size_t)(512 + w*64)*8]);
    }
  };
  auto stageR64 = [&](int ar0) {
    const char* rg = rkb + (size_t)ar0 * 128;
    int ck = tid;
    int grow = ck >> 3, gcol = (ck & 7) ^ (grow & 7);
    async16(rg + (size_t)grow*128 + gcol*16, &Rt[(size_t)((ar0 & 255) + w*8)*64]);
  };

  // ---- prologue: K(jt0), full 192-row band, V(jt0); drain once
  {
    const int k00 = jt0*64 - i0 + (LQ - 128);
    stageK(jt0);
    stageR64(k00); stageR64(k00 + 64); stageR64(k00 + 128);
    stageV(jt0);
  }
  __syncthreads();

  for (int jt = jt0; jt < jtend; ++jt) {
    const int k0 = jt*64 - i0 + (LQ - 128);
    const int kb = k0 & 255;

    // ---- [A] content + rel scores
    f32x4_t accc[4] = {fz, fz, fz, fz};
    f32x4_t accr[5] = {fz, fz, fz, fz, fz};
    #pragma unroll
    for (int ns = 0; ns < 4; ++ns) {
      int row = ns*16 + s;
      Frag b0; b0.u = *(const u16x8_t*)&Kt[(size_t)(row*8 + swz0)*8];
      Frag b1; b1.u = *(const u16x8_t*)&Kt[(size_t)(row*8 + swz1)*8];
      accc[ns] = __builtin_amdgcn_mfma_f32_16x16x32_bf16(qwf[0].b, b0.b, accc[ns], 0, 0, 0);
      accc[ns] = __builtin_amdgcn_mfma_f32_16x16x32_bf16(qwf[1].b, b1.b, accc[ns], 0, 0, 0);
    }
    #pragma unroll
    for (int nn = 0; nn < 5; ++nn) {
      int row = (kb + (7 - w + nn)*16 + s) & 255;
      Frag b0; b0.u = *(const u16x8_t*)&Rt[(size_t)(row*8 + swz0)*8];
      Frag b1; b1.u = *(const u16x8_t*)&Rt[(size_t)(row*8 + swz1)*8];
      accr[nn] = __builtin_amdgcn_mfma_f32_16x16x32_bf16(qrf[0].b, b0.b, accr[nn], 0, 0, 0);
      accr[nn] = __builtin_amdgcn_mfma_f32_16x16x32_bf16(qrf[1].b, b1.b, accr[nn], 0, 0, 0);
    }

    // sync1: all waves done reading Kt/ring; drains V(jt) DMA
    __syncthreads();

    // ---- prefetch K + new 64 ring rows for jt+1 (hides under [B])
    if (jt + 1 < jtend) {
      stageK(jt + 1);
      stageR64(k0 + 192);
    }

    // ---- [B] diagonal shift via bpermute
    #pragma unroll
    for (int r = 0; r < 4; ++r) {
      int tt = s + 15 - 4*q - r;               // [0,30]
      int srcl = (lane & 48) | (tt & 15);
      bool hi = tt >= 16;
      float v[5];
      #pragma unroll
      for (int nn = 0; nn < 5; ++nn) v[nn] = __shfl(accr[nn][r], srcl, 64);
      #pragma unroll
      for (int ns = 0; ns < 4; ++ns)
        accc[ns][r] += hi ? v[ns + 1] : v[ns];
    }

    // ---- [B] online softmax (DPP max; sum via ones-MFMA)
    #pragma unroll
    for (int r = 0; r < 4; ++r) {
      float mx = fmaxf(fmaxf(accc[0][r], accc[1][r]), fmaxf(accc[2][r], accc[3][r]));
      mx = rowmax16(mx);
      float mnew  = fmaxf(mrun[r], mx);
      float alpha = __expf(mrun[r] - mnew);
      #pragma unroll
      for (int ns = 0; ns < 4; ++ns)
        accc[ns][r] = __expf(accc[ns][r] - mnew);
      mrun[r] = mnew;
      accl[r] *= alpha;
      #pragma unroll
      for (int vs = 0; vs < 6; ++vs) acco[vs][r] *= alpha;
    }

    // ---- [B] P: C-layout -> per-wave LDS -> A-layout
    #pragma unroll
    for (int ns = 0; ns < 4; ++ns)
      #pragma unroll
      for (int r = 0; r < 4; ++r)
        Ps[w][q*4 + r][ns*16 + s] = f2bf_hw(accc[ns][r]);

    // ---- [B] PV + ones-column row-sum
    #pragma unroll
    for (int kf = 0; kf < 2; ++kf) {
      Frag pf; pf.u = *(const u16x8_t*)(&Ps[w][s][kf*32 + q*8]);
      int sw = kf ? swz1 : swz0;
      #pragma unroll
      for (int vs = 0; vs < 6; ++vs) {
        int row = vs*16 + s;
        Frag vf; vf.u = *(const u16x8_t*)&Vs[(size_t)(row*8 + sw)*8];
        acco[vs] = __builtin_amdgcn_mfma_f32_16x16x32_bf16(pf.b, vf.b, acco[vs], 0, 0, 0);
      }
      accl = __builtin_amdgcn_mfma_f32_16x16x32_bf16(pf.b, ones.b, accl, 0, 0, 0);
    }

    // sync2: all waves done reading Vs/Ps; drains K/ring DMA
    __syncthreads();

    // ---- prefetch V for jt+1 (hides under next [A])
    if (jt + 1 < jtend) stageV(jt + 1);
  }

  // ---- epilogue
  if (nz == 1) {
    #pragma unroll
    for (int r = 0; r < 4; ++r) {
      float inv = frcp(accl[r]);
      int i = i0 + 16*w + q*4 + r;
      #pragma unroll
      for (int vs = 0; vs < 6; ++vs) {
        int v = vs*16 + s;
        attnO[((size_t)b*LQ + i)*768 + h*96 + v] = f2bf_hw(acco[vs][r] * inv);
      }
    }
  } else {
    #pragma unroll
    for (int vs = 0; vs < 6; ++vs) {
      int v = vs*16 + s;
      #pragma unroll
      for (int r = 0; r < 4; ++r) {
        int i = i0 + 16*w + q*4 + r;
        size_t rg = (size_t)(z*32 + bh)*LQ + i;
        Opart[rg*96 + v] = f2bf_hw(acco[vs][r]);
      }
    }
    if (s == 0) {
      #pragma unroll
      for (int r = 0; r < 4; ++r) {
        int i = i0 + 16*w + q*4 + r;
        size_t rg = (size_t)(z*32 + bh)*LQ + i;
        ml[rg*2 + 0] = mrun[r];
        ml[rg*2 + 1] = accl[r];
      }
    }
  }
}

// ---------------------------------------------------------------------------
// K5b: flash combine of nz j-partials -> attnO bf16.
// Vectorized u16x8 (8 v-elems/thread), grid 2304 x 256.
// ---------------------------------------------------------------------------
__global__ void combine_k(const u16* __restrict__ Opart, const float* __restrict__ ml,
                          u16* __restrict__ attnO, int nz)
{
  int g = blockIdx.x * 256 + threadIdx.x;     // one (row, 8-v-group) per thread
  if (g >= 32*LQ*12) return;
  int vg = g % 12, row = g / 12;
  int v0 = vg * 8;
  int bh = row / LQ, i = row - bh*LQ;
  int b = bh >> 3, h = bh & 7;
  float M = -1e30f;
  for (int z = 0; z < nz; ++z)
    M = fmaxf(M, ml[((size_t)(z*32 + bh)*LQ + i)*2]);
  float L = 0.f;
  float num[8];
  #pragma unroll
  for (int j = 0; j < 8; ++j) num[j] = 0.f;
  for (int z = 0; z < nz; ++z) {
    size_t rg = (size_t)(z*32 + bh)*LQ + i;
    float e = __expf(ml[rg*2] - M);
    L += ml[rg*2 + 1] * e;
    u16x8_t ov = *(const u16x8_t*)&Opart[rg*96 + v0];
    #pragma unroll
    for (int j = 0; j < 8; ++j) num[j] += bf2f(ov[j]) * e;
  }
  float invL = frcp(L);
  u16x8_t outv;
  #pragma unroll
  for (int j = 0; j < 8; ++j) outv[j] = f2bf(num[j] * invL);
  *(u16x8_t*)&attnO[((size_t)b*LQ + i)*768 + h*96 + v0] = outv;
}

// ---------------------------------------------------------------------------
// K6: output projection (M=6144, N=768, K=768) + bias -> d_out FLOAT.
// 64x64 tile. grid (12,96).
// ---------------------------------------------------------------------------
__global__ __launch_bounds__(256) void out_gemm(
    const u16* __restrict__ A, const u16* __restrict__ Wt,
    const float* __restrict__ bias, float* __restrict__ out)
{
  const int n0 = blockIdx.x * 64;
  const int m0 = blockIdx.y * 64;
  const int tid = threadIdx.x, w = tid >> 6, lane = tid & 63, q = lane >> 4, s = lane & 15;

  __shared__ __align__(16) u16 At[64*64];
  __shared__ __align__(16) u16 Bt[64*64];

  const char* ag = (const char*)(A  + (size_t)m0 * 768);
  const char* bg = (const char*)(Wt + (size_t)n0 * 768);

  const f32x4_t fz = {0.f, 0.f, 0.f, 0.f};
  f32x4_t acc[4] = {fz, fz, fz, fz};

  for (int kk = 0; kk < 768; kk += 64) {
    #pragma unroll
    for (int c = 0; c < 2; ++c) {
      int ck = w*128 + c*64 + lane;
      int grow = ck >> 3, gcol = (ck & 7) ^ (grow & 7);
      async16(ag + (size_t)grow*1536 + (size_t)(kk + gcol*8)*2, &At[(size_t)(w*128 + c*64)*8]);
      async16(bg + (size_t)grow*1536 + (size_t)(kk + gcol*8)*2, &Bt[(size_t)(w*128 + c*64)*8]);
    }
    __syncthreads();
    #pragma unroll
    for (int kf = 0; kf < 2; ++kf) {
      int sw = (kf*4 + q) ^ (s & 7);
      Frag af; af.u = *(const u16x8_t*)&At[(size_t)((16*w + s)*8 + sw)*8];
      #pragma unroll
      for (int ns = 0; ns < 4; ++ns) {
        Frag bf; bf.u = *(const u16x8_t*)&Bt[(size_t)((ns*16 + s)*8 + sw)*8];
        acc[ns] = __builtin_amdgcn_mfma_f32_16x16x32_bf16(af.b, bf.b, acc[ns], 0, 0, 0);
      }
    }
    __syncthreads();
  }

  #pragma unroll
  for (int ns = 0; ns < 4; ++ns) {
    int c = n0 + ns*16 + s;
    float bv = bias[c];
    #pragma unroll
    for (int r = 0; r < 4; ++r) {
      int row = m0 + 16*w + q*4 + r;
      out[(size_t)row*768 + c] = acc[ns][r] + bv;
    }
  }
}

// ---------------------------------------------------------------------------
extern "C" void kernel_launch(void* const* d_in, const int* in_sizes, int n_in,
                              void* d_out, int out_size, void* d_ws, size_t ws_size,
                              hipStream_t stream)
{
  (void)out_size;

  static const int dict_sig[9] = {4718592,393216,393216,589824,589824,768,49152,512,512};
  bool is_dict = (n_in == 9);
  for (int i = 0; i < 9 && i < n_in; ++i)
    if (in_sizes[i] != dict_sig[i]) is_dict = false;

  const float *x, *Qw_w, *Kw_w, *Vw_w, *Ow_w, *out_b, *relKw, *rwb, *rrb;
  if (is_dict) {
    x     = (const float*)d_in[0];  Qw_w  = (const float*)d_in[1];
    Kw_w  = (const float*)d_in[2];  Vw_w  = (const float*)d_in[3];
    Ow_w  = (const float*)d_in[4];  out_b = (const float*)d_in[5];
    relKw = (const float*)d_in[6];  rwb   = (const float*)d_in[7];
    rrb   = (const float*)d_in[8];
  } else {
    const float* p393[2] = {nullptr,nullptr}; int n393 = 0;
    const float* p589[2] = {nullptr,nullptr}; int n589 = 0;
    const float* p512[2] = {nullptr,nullptr}; int n512 = 0;
    const float *px = nullptr, *prel = nullptr, *pb = nullptr;
    for (int i = 0; i < n_in; ++i) {
      const float* p = (const float*)d_in[i];
      switch (in_sizes[i]) {
        case 4718592: px = p; break;
        case 49152:   prel = p; break;
        case 768:     pb = p; break;
        case 393216:  if (n393 < 2) p393[n393++] = p; break;
        case 589824:  if (n589 < 2) p589[n589++] = p; break;
        case 512:     if (n512 < 2) p512[n512++] = p; break;
        default: break;
      }
    }
    x = px; relKw = prel; out_b = pb;
    Qw_w = p393[0]; Kw_w = p393[1];
    Vw_w = p589[0]; Ow_w = p589[1];
    rwb  = p512[0]; rrb  = p512[1];
  }

  float* out = (float*)d_out;

  char* ws = (char*)d_ws;
  size_t off = 0;
  auto alloc = [&](size_t bytes) -> void* {
    void* p = ws + off;
    off += (bytes + 255) & ~(size_t)255;
    return p;
  };

  u16*   WtQKV = (u16*)  alloc((size_t)1792*768*2);   // 2.75 MB
  u16*   WtOut = (u16*)  alloc((size_t)768*768*2);    // 1.18 MB
  u16*   rK    = (u16*)  alloc((size_t)8*NPOSP*64*2); // 3 MB
  u16*   Qb    = (u16*)  alloc((size_t)32*LQ*64*2);   // 6.3 MB
  u16*   Kc    = (u16*)  alloc((size_t)32*LQ*64*2);   // 6.3 MB
  u16*   Vt    = (u16*)  alloc((size_t)32*96*LQ*2);   // 9.4 MB
  u16*   xb    = (u16*)  alloc((size_t)6144*768*2);   // 9.4 MB
  u16*   attnO = xb;  // alias: xb dead after qkv_gemm

  // pick nz by workspace headroom (partials = nz*(9.44 MB + 0.39 MB))
  size_t base_off = off;
  auto need = [&](int nzv) -> size_t {
    size_t o = base_off;
    o += (((size_t)nzv*32*LQ*96*2) + 255) & ~(size_t)255;
    o += (((size_t)nzv*32*LQ*2*4) + 255) & ~(size_t)255;
    return o;
  };
  int nz = 1;
  if (ws_size >= need(4)) nz = 4;
  else if (ws_size >= need(2)) nz = 2;
  u16*   Opart = nullptr; float* ml = nullptr;
  if (nz > 1) {
    Opart = (u16*)  alloc((size_t)nz*32*LQ*96*2);
    ml    = (float*)alloc((size_t)nz*32*LQ*2*4);
  }

  pre_k      <<<dim3(3552), dim3(256), 0, stream>>>(x, Qw_w, Kw_w, Vw_w, Ow_w,
                                                    relKw, xb, WtQKV, WtOut, rK);
  qkv_gemm   <<<dim3(14,48),dim3(256), 0, stream>>>(xb, WtQKV, Qb, Kc, Vt);
  attn_k     <<<dim3(384*nz),dim3(512), 0, stream>>>(Qb, Kc, Vt, rK, rwb, rrb,
                                                     attnO, Opart, ml, nz);
  if (nz > 1)
    combine_k<<<dim3(2304),  dim3(256), 0, stream>>>(Opart, ml, attnO, nz);
  out_gemm   <<<dim3(12,96),dim3(256), 0, stream>>>(attnO, WtOut, out_b, out);
}